// Round 2
// baseline (10177.072 us; speedup 1.0000x reference)
//
#include <hip/hip_runtime.h>
#include <hip/hip_bf16.h>

#define B_ 4
#define S_ 2048
#define D_ 1024
#define H_ 16
#define HD_ 64

typedef short short8 __attribute__((ext_vector_type(8)));
typedef float f32x4 __attribute__((ext_vector_type(4)));

__device__ __forceinline__ float bf2f(unsigned short u) {
    union { unsigned int i; float f; } v; v.i = ((unsigned int)u) << 16; return v.f;
}
__device__ __forceinline__ unsigned short f2bf(float f) {
    union { float f; unsigned int i; } v; v.f = f;
    unsigned int x = v.i;
    unsigned int r = (x + 0x7fffu + ((x >> 16) & 1u)) >> 16;
    return (unsigned short)r;
}
// Load 8 consecutive f32, round-to-nearest-even to bf16, pack for MFMA frag.
__device__ __forceinline__ short8 load8_f32_bf16(const float* __restrict__ p) {
    f32x4 lo = *(const f32x4*)p;
    f32x4 hi = *(const f32x4*)(p + 4);
    short8 r;
    r[0] = (short)f2bf(lo[0]); r[1] = (short)f2bf(lo[1]);
    r[2] = (short)f2bf(lo[2]); r[3] = (short)f2bf(lo[3]);
    r[4] = (short)f2bf(hi[0]); r[5] = (short)f2bf(hi[1]);
    r[6] = (short)f2bf(hi[2]); r[7] = (short)f2bf(hi[3]);
    return r;
}

// C[M,N] = A[M,K] @ W[N,K]^T + bias[N], fp32 accum via mfma_f32_16x16x32_bf16.
// A_BF16: A is bf16 (ws) else f32 (input). C_BF16: C written bf16 (ws) else f32.
// One wave = one 16x16 tile. A-frag: lane -> A[m=lane&15][k0+(lane>>4)*8+j];
// D: lane,reg -> row=(lane>>4)*4+reg, col=lane&15  (verified mapping, guide §3)
template<int A_BF16, int C_BF16>
__global__ __launch_bounds__(256) void gemm_nt_bias(
    const void* __restrict__ Av,
    const float* __restrict__ W,
    const float* __restrict__ bias,
    void* __restrict__ Cv,
    int M, int N, int K)
{
    int lane = threadIdx.x & 63;
    int w    = threadIdx.x >> 6;
    int n_base = (blockIdx.x * 4 + w) * 16;
    int m_base = blockIdx.y * 16;
    int r16  = lane & 15;
    int koff = (lane >> 4) * 8;

    f32x4 acc = {0.f, 0.f, 0.f, 0.f};
    for (int k0 = 0; k0 < K; k0 += 32) {
        short8 a, b;
        if (A_BF16) {
            const unsigned short* ap =
                (const unsigned short*)Av + (size_t)(m_base + r16) * K + koff + k0;
            a = *(const short8*)ap;
        } else {
            const float* ap = (const float*)Av + (size_t)(m_base + r16) * K + koff + k0;
            a = load8_f32_bf16(ap);
        }
        const float* bp = W + (size_t)(n_base + r16) * K + koff + k0;
        b = load8_f32_bf16(bp);
        acc = __builtin_amdgcn_mfma_f32_16x16x32_bf16(a, b, acc, 0, 0, 0);
    }

    int col  = n_base + r16;
    float bvl = bias[col];
    int row0 = m_base + (lane >> 4) * 4;
    #pragma unroll
    for (int r = 0; r < 4; ++r) {
        float v = acc[r] + bvl;
        if (C_BF16)
            ((unsigned short*)Cv)[(size_t)(row0 + r) * N + col] = f2bf(v);
        else
            ((float*)Cv)[(size_t)(row0 + r) * N + col] = v;
    }
}

// One block per (b, h, q-row): scores -> mask -> softmax -> f32 probs to d_out.
// Q/K staged in ws as bf16.
__global__ __launch_bounds__(256) void attn_scores(
    const unsigned short* __restrict__ Q,
    const unsigned short* __restrict__ Kp,
    const int* __restrict__ mask,
    float* __restrict__ probs)
{
    int s = blockIdx.x;
    int h = blockIdx.y;
    int b = blockIdx.z;
    __shared__ float qs[HD_];
    __shared__ float sc[S_];
    __shared__ float red[256];
    int t = threadIdx.x;

    if (t < HD_) qs[t] = bf2f(Q[((size_t)(b * S_ + s)) * D_ + h * HD_ + t]);
    __syncthreads();

    const float scale = 0.125f; // 1/sqrt(64)
    float lmax = -3.4e38f;
    #pragma unroll
    for (int i = 0; i < S_ / 256; ++i) {
        int k = t + i * 256;
        const unsigned short* kr = Kp + ((size_t)(b * S_ + k)) * D_ + h * HD_;
        float dot = 0.f;
        #pragma unroll
        for (int j = 0; j < HD_ / 8; ++j) {
            short8 kv = *(const short8*)(kr + j * 8);
            #pragma unroll
            for (int e = 0; e < 8; ++e)
                dot += qs[j * 8 + e] * bf2f((unsigned short)kv[e]);
        }
        float v = (mask[b * S_ + k] == 0) ? -1e10f : dot * scale;
        sc[k] = v;
        lmax = fmaxf(lmax, v);
    }

    red[t] = lmax; __syncthreads();
    for (int off = 128; off > 0; off >>= 1) {
        if (t < off) red[t] = fmaxf(red[t], red[t + off]);
        __syncthreads();
    }
    float m = red[0];
    __syncthreads();

    float lsum = 0.f;
    #pragma unroll
    for (int i = 0; i < S_ / 256; ++i) {
        int k = t + i * 256;
        float e = __expf(sc[k] - m);
        sc[k] = e;
        lsum += e;
    }
    red[t] = lsum; __syncthreads();
    for (int off = 128; off > 0; off >>= 1) {
        if (t < off) red[t] += red[t + off];
        __syncthreads();
    }
    float inv = 1.f / red[0];

    float* prow = probs + (((size_t)(b * H_ + h) * S_) + s) * S_;
    #pragma unroll
    for (int i = 0; i < S_ / 256; ++i) {
        int k = t + i * 256;
        prow[k] = sc[k] * inv;
    }
}

// One block per (b, h, q-row): x_h[s,:] = sum_k P[s,k] * V_h[k,:]
// probs f32 (d_out), V bf16 (ws), X bf16 (ws). Lane = head dim -> coalesced V reads.
__global__ __launch_bounds__(256) void attn_pv(
    const float* __restrict__ probs,
    const unsigned short* __restrict__ V,
    unsigned short* __restrict__ X)
{
    int s = blockIdx.x;
    int h = blockIdx.y;
    int b = blockIdx.z;
    __shared__ float ps[S_];
    __shared__ float red[4][HD_];
    int t = threadIdx.x;

    const float* prow = probs + (((size_t)(b * H_ + h) * S_) + s) * S_;
    #pragma unroll
    for (int i = 0; i < S_ / 256; ++i) ps[t + i * 256] = prow[t + i * 256];
    __syncthreads();

    int d = t & 63;
    int q = t >> 6;
    const unsigned short* vbase = V + ((size_t)b * S_) * D_ + h * HD_ + d;
    float acc = 0.f;
    int k0 = q * (S_ / 4);
    for (int k = k0; k < k0 + S_ / 4; ++k) {
        acc += ps[k] * bf2f(vbase[(size_t)k * D_]);
    }
    red[q][d] = acc;
    __syncthreads();
    if (t < HD_) {
        float v = red[0][t] + red[1][t] + red[2][t] + red[3][t];
        X[((size_t)(b * S_ + s)) * D_ + h * HD_ + t] = f2bf(v);
    }
}

extern "C" void kernel_launch(void* const* d_in, const int* in_sizes, int n_in,
                              void* d_out, int out_size, void* d_ws, size_t ws_size,
                              hipStream_t stream) {
    (void)in_sizes; (void)n_in; (void)out_size; (void)ws_size;

    const float* query = (const float*)d_in[0];
    const float* key   = (const float*)d_in[1];
    const float* value = (const float*)d_in[2];
    const int*   mask  = (const int*)d_in[3];
    const float* Wq = (const float*)d_in[4];
    const float* bq = (const float*)d_in[5];
    const float* Wk = (const float*)d_in[6];
    const float* bk = (const float*)d_in[7];
    const float* Wv = (const float*)d_in[8];
    const float* bv = (const float*)d_in[9];
    const float* Wo = (const float*)d_in[10];
    const float* bo = (const float*)d_in[11];

    const size_t NTOK = (size_t)B_ * S_ * D_; // 8388608
    unsigned short* Qp = (unsigned short*)d_ws;    // bf16 [B,S,D]
    unsigned short* Kp = Qp + NTOK;                // bf16 [B,S,D]
    unsigned short* Vp = Kp + NTOK;                // bf16 [B,S,D]
    unsigned short* Xc = Vp + NTOK;                // bf16 [B,S,D]

    float* out_x = (float*)d_out;                  // f32 [B,S,D]
    float* out_p = out_x + NTOK;                   // f32 [B,H,S,S]

    dim3 gblk(256);
    dim3 ggrid(D_ / 64, (B_ * S_) / 16);
    gemm_nt_bias<0,1><<<ggrid, gblk, 0, stream>>>(query, Wq, bq, Qp, B_ * S_, D_, D_);
    gemm_nt_bias<0,1><<<ggrid, gblk, 0, stream>>>(key,   Wk, bk, Kp, B_ * S_, D_, D_);
    gemm_nt_bias<0,1><<<ggrid, gblk, 0, stream>>>(value, Wv, bv, Vp, B_ * S_, D_, D_);

    dim3 agrid(S_, H_, B_);
    attn_scores<<<agrid, gblk, 0, stream>>>(Qp, Kp, mask, out_p);
    attn_pv<<<agrid, gblk, 0, stream>>>(out_p, Vp, Xc);

    gemm_nt_bias<1,0><<<ggrid, gblk, 0, stream>>>(Xc, Wo, bo, out_x, B_ * S_, D_, D_);
}